// Round 10
// baseline (168.142 us; speedup 1.0000x reference)
//
#include <hip/hip_runtime.h>

#define HW   (256*256)        // 65536
#define VOL  (64*HW)          // 4194304 per batch volume
#define NTOT (4ull*VOL)
#define C1v  1e-4f
#define C2v  9e-4f
#define EPSv 1e-8f

typedef float    f2 __attribute__((ext_vector_type(2)));
typedef float    f4 __attribute__((ext_vector_type(4)));
typedef _Float16 h2 __attribute__((ext_vector_type(2)));
typedef _Float16 h4 __attribute__((ext_vector_type(4)));
typedef _Float16 h8 __attribute__((ext_vector_type(8)));

// ws layout:
// [0      .. 63]     : w[11] float (1D separable weights)
// [64     .. 16447]  : partials[2048] double
// [16640  .. ]       : packed field volumes, 10 bytes/element per batch:
//                      F0 = h2{X,Y}[VOL], F1 = h2{XX,YY}[VOL], F2 = f16 XY[VOL]

__global__ void init_weights(const float* __restrict__ k3, float* __restrict__ w) {
    int i = threadIdx.x;
    if (i < 11) {
        float s = 0.f;
        for (int t = 0; t < 121; ++t) s += k3[i * 121 + t];
        w[i] = s;   // k3 is separable: row-sum = 1D weight
    }
}

// Pass 1 via MFMA banded matmuls (bank-conflict-free, LDS-aliased).
//  P[f][32][88] fp16 products (rows 26..31 + halo zeros, predicated loads)
//  W-conv: A=data(16x32) x B=band WB -> regs; barrier; write Tt (ALIASED over P)
//  Tt[f][64][40]: col-major transpose; H-conv: A=band AH x B=Tt -> packed stores
// grid: (4, 16, 64*nb) x 256.
__global__ __launch_bounds__(256) void blur_hw(
    const float* __restrict__ x, const float* __restrict__ y,
    const float* __restrict__ w11, char* __restrict__ fields, int b0)
{
    __shared__ alignas(16) _Float16 PB[5 * 32 * 88];  // 28,160 B; Tt (25,600 B) aliases
    __shared__ alignas(16) _Float16 WB[16][40];       //  1,280 B (pad col 40 for banks)
    __shared__ alignas(16) _Float16 AH[16][40];       //  1,280 B   -> 30,720 B total

    const int d   = blockIdx.z & 63;
    const int bz  = blockIdx.z >> 6;
    const int h0  = blockIdx.y * 16;
    const int w0  = blockIdx.x * 64;
    const int tid = threadIdx.x;

    // ---- band tables: 512 items (k<32; pad cols 32..39 never read) ----
#pragma unroll
    for (int it = 0; it < 2; ++it) {
        int t = tid + it * 256;
        int n = t >> 5, k = t & 31;
        int i1 = k - n - 1;                 // W band (staged-col shift +1)
        int i2 = k - n;                     // H band
        float v1 = ((unsigned)i1 <= 10u) ? w11[min(max(i1, 0), 10)] : 0.f;
        float v2 = ((unsigned)i2 <= 10u) ? w11[min(max(i2, 0), 10)] : 0.f;
        WB[n][k] = (_Float16)v1;
        AH[n][k] = (_Float16)v2;
    }

    const float* xb = x + (size_t)(b0 + bz) * VOL + (size_t)d * HW;
    const float* yb = y + (size_t)(b0 + bz) * VOL + (size_t)d * HW;

    // ---- stage products: 32 rows x 44 col-pairs = 1408 items, predicated loads ----
    for (int it = 0; it < 6; ++it) {
        int p = tid + it * 256;
        if (p < 1408) {
            int r = p / 44, j = p - r * 44;
            int gh = h0 - 5 + r;
            int gw = w0 - 6 + 2 * j;        // even
            f2 xv = {0.f, 0.f}, yv = {0.f, 0.f};
            if (r < 26 && (unsigned)gh < 256u && (unsigned)gw < 256u) {
                int idx = gh * 256 + gw;
                xv = *(const f2*)&xb[idx];
                yv = *(const f2*)&yb[idx];
            }
            _Float16* pb = PB + r * 88 + j * 2;          // field stride 2816 halves
            *(h2*)(pb + 0)     = (h2){(_Float16)xv[0], (_Float16)xv[1]};
            *(h2*)(pb + 2816)  = (h2){(_Float16)yv[0], (_Float16)yv[1]};
            *(h2*)(pb + 5632)  = (h2){(_Float16)(xv[0]*xv[0]), (_Float16)(xv[1]*xv[1])};
            *(h2*)(pb + 8448)  = (h2){(_Float16)(yv[0]*yv[0]), (_Float16)(yv[1]*yv[1])};
            *(h2*)(pb + 11264) = (h2){(_Float16)(xv[0]*yv[0]), (_Float16)(xv[1]*yv[1])};
        }
    }
    __syncthreads();

    const int lane = tid & 63, wid = tid >> 6;
    const int lm = lane & 15, lk = lane >> 4;

    // ---- W-conv into registers: wave = N-chunk; 5 fields x 2 M-chunks ----
    h4 wres[10];
    {
        h8 bw = *(const h8*)((const char*)WB + lm * 80 + lk * 16);
        const char* Ab = (const char*)PB + lm * 176 + wid * 32 + lk * 16;
#pragma unroll
        for (int f = 0; f < 5; ++f) {
#pragma unroll
            for (int mc = 0; mc < 2; ++mc) {
                h8 a = *(const h8*)(Ab + f * 5632 + mc * 2816);
                f4 dv = __builtin_amdgcn_mfma_f32_16x16x32_f16(
                            a, bw, (f4){0.f, 0.f, 0.f, 0.f}, 0, 0, 0);
                wres[f * 2 + mc] = (h4){(_Float16)dv[0], (_Float16)dv[1],
                                        (_Float16)dv[2], (_Float16)dv[3]};
            }
        }
    }
    __syncthreads();    // all P reads done -> safe to overwrite with Tt

    // ---- write transposed Tt[f][col64][row40] aliased over PB ----
    {
        char* Tb = (char*)PB + (wid * 16 + lm) * 80 + lk * 8;
#pragma unroll
        for (int f = 0; f < 5; ++f) {
#pragma unroll
            for (int mc = 0; mc < 2; ++mc) {
                *(h4*)(Tb + f * 5120 + mc * 32) = wres[f * 2 + mc];
            }
        }
    }
    __syncthreads();

    // ---- H-conv: wave = N-chunk; 5 fields, then packed stores ----
    {
        h8 ah = *(const h8*)((const char*)AH + lm * 80 + lk * 16);
        const char* Tb = (const char*)PB + (wid * 16 + lm) * 80 + lk * 16;
        f4 d0 = __builtin_amdgcn_mfma_f32_16x16x32_f16(ah, *(const h8*)(Tb + 0),
                    (f4){0.f,0.f,0.f,0.f}, 0, 0, 0);
        f4 d1 = __builtin_amdgcn_mfma_f32_16x16x32_f16(ah, *(const h8*)(Tb + 5120),
                    (f4){0.f,0.f,0.f,0.f}, 0, 0, 0);
        f4 d2 = __builtin_amdgcn_mfma_f32_16x16x32_f16(ah, *(const h8*)(Tb + 10240),
                    (f4){0.f,0.f,0.f,0.f}, 0, 0, 0);
        f4 d3 = __builtin_amdgcn_mfma_f32_16x16x32_f16(ah, *(const h8*)(Tb + 15360),
                    (f4){0.f,0.f,0.f,0.f}, 0, 0, 0);
        f4 d4 = __builtin_amdgcn_mfma_f32_16x16x32_f16(ah, *(const h8*)(Tb + 20480),
                    (f4){0.f,0.f,0.f,0.f}, 0, 0, 0);

        h2* F0 = (h2*)(fields + (size_t)bz * 10 * VOL);
        h2* F1 = F0 + (size_t)VOL;
        _Float16* F2 = (_Float16*)(F1 + (size_t)VOL);

        const int col = w0 + wid * 16 + lm;
#pragma unroll
        for (int rg = 0; rg < 4; ++rg) {
            int row = lk * 4 + rg;
            size_t oi = (size_t)d * HW + (size_t)(h0 + row) * 256 + col;
            F0[oi] = (h2){(_Float16)d0[rg], (_Float16)d1[rg]};
            F1[oi] = (h2){(_Float16)d2[rg], (_Float16)d3[rg]};
            F2[oi] = (_Float16)d4[rg];
        }
    }
}

// Pass 2: D-conv via scalar fp32 register rings, packed field loads.
// DHALF compile-time so ALL guards fold; grid: (256, nb) x 256.
template<int DHALF>
__global__ __launch_bounds__(256) void dconv_ssim(
    const char* __restrict__ fields, const float* __restrict__ w11,
    double* __restrict__ partials, int b0)
{
    const int col = blockIdx.x * 256 + threadIdx.x;  // 0..65535 within slice
    const int bz  = blockIdx.y;

    float wl[11];
#pragma unroll
    for (int t = 0; t < 11; ++t) wl[t] = w11[t];

    const h2* F0 = (const h2*)(fields + (size_t)bz * 10 * VOL);
    const h2* F1 = F0 + (size_t)VOL;
    const _Float16* F2 = (const _Float16*)(F1 + (size_t)VOL);

    float bX[11], bY[11], bXX[11], bYY[11], bXY[11];
#pragma unroll
    for (int t = 0; t < 11; ++t) { bX[t] = 0; bY[t] = 0; bXX[t] = 0; bYY[t] = 0; bXY[t] = 0; }

    float acc = 0.f;
#pragma unroll
    for (int s = 0; s < 42; ++s) {
        const int dd = DHALF * 32 - 5 + s;          // compile-time after unroll
        const int slot = s % 11;                    // compile-time
        if (dd >= 0 && dd < 64) {                   // compile-time
            size_t idx = (size_t)dd * HW + col;
            h2 v0 = F0[idx];
            h2 v1 = F1[idx];
            _Float16 vxy = F2[idx];
            bX[slot]  = (float)v0[0];
            bY[slot]  = (float)v0[1];
            bXX[slot] = (float)v1[0];
            bYY[slot] = (float)v1[1];
            bXY[slot] = (float)vxy;
        } else {
            bX[slot] = 0; bY[slot] = 0; bXX[slot] = 0; bYY[slot] = 0; bXY[slot] = 0;
        }

        if (s >= 10) {                              // compile-time; emit depth DHALF*32 + s-10
            float mX = 0, mY = 0, cXX = 0, cYY = 0, cXY = 0;
#pragma unroll
            for (int t = 0; t < 11; ++t) {
                const int j = (s + 1 + t) % 11;     // compile-time
                float wt = wl[t];
                mX  += wt * bX[j];
                mY  += wt * bY[j];
                cXX += wt * bXX[j];
                cYY += wt * bYY[j];
                cXY += wt * bXY[j];
            }
            float mx2 = mX * mX, my2 = mY * mY, mxy = mX * mY;
            float sx2 = cXX - mx2, sy2 = cYY - my2, sxy = cXY - mxy;
            float num = (2.f * mxy + C1v) * (2.f * sxy + C2v);
            float den = (mx2 + my2 + C1v) * (sx2 + sy2 + C2v);
            acc += num * __builtin_amdgcn_rcpf(den + EPSv);
        }
    }

    // reduce 256 threads -> one partial per block (deterministic)
    for (int off = 32; off; off >>= 1) acc += __shfl_down(acc, off, 64);
    __shared__ float wsum[4];
    int lane = threadIdx.x & 63, wid = threadIdx.x >> 6;
    if (lane == 0) wsum[wid] = acc;
    __syncthreads();
    if (threadIdx.x == 0) {
        float s = wsum[0] + wsum[1] + wsum[2] + wsum[3];
        partials[(size_t)(b0 + bz) * 512 + DHALF * 256 + blockIdx.x] = (double)s;
    }
}

__global__ void finalize(const double* __restrict__ partials, float* __restrict__ out, int n) {
    __shared__ double sh[256];
    double s = 0.0;
    for (int i = threadIdx.x; i < n; i += 256) s += partials[i];
    sh[threadIdx.x] = s;
    __syncthreads();
    for (int stride = 128; stride; stride >>= 1) {
        if (threadIdx.x < stride) sh[threadIdx.x] += sh[threadIdx.x + stride];
        __syncthreads();
    }
    if (threadIdx.x == 0) out[0] = 1.0f - (float)(sh[0] / (double)NTOT);
}

extern "C" void kernel_launch(void* const* d_in, const int* in_sizes, int n_in,
                              void* d_out, int out_size, void* d_ws, size_t ws_size,
                              hipStream_t stream) {
    const float* x  = (const float*)d_in[0];
    const float* y  = (const float*)d_in[1];
    const float* k3 = (const float*)d_in[2];
    float* out = (float*)d_out;

    char* ws = (char*)d_ws;
    float*   w11      = (float*)ws;
    double*  partials = (double*)(ws + 64);
    char*    fields   = ws + 16640;

    const size_t perBatch = (size_t)10 * VOL;   // packed fp16 fields per batch (bytes)
    const bool all4 = ws_size >= 16640 + 4 * perBatch;

    init_weights<<<1, 64, 0, stream>>>(k3, w11);

    if (all4) {
        blur_hw      <<<dim3(4, 16, 256), 256, 0, stream>>>(x, y, w11, fields, 0);
        dconv_ssim<0><<<dim3(256, 4),     256, 0, stream>>>(fields, w11, partials, 0);
        dconv_ssim<1><<<dim3(256, 4),     256, 0, stream>>>(fields, w11, partials, 0);
    } else {
        for (int b = 0; b < 4; ++b) {
            blur_hw      <<<dim3(4, 16, 64), 256, 0, stream>>>(x, y, w11, fields, b);
            dconv_ssim<0><<<dim3(256, 1),    256, 0, stream>>>(fields, w11, partials, b);
            dconv_ssim<1><<<dim3(256, 1),    256, 0, stream>>>(fields, w11, partials, b);
        }
    }

    finalize<<<1, 256, 0, stream>>>(partials, out, 2048);
}